// Round 1
// baseline (1004.557 us; speedup 1.0000x reference)
//
#include <hip/hip_runtime.h>
#include <hip/hip_bf16.h>

#define N_TX   500000
#define N_ACC  100000
#define E_CNT  1000000
#define D_TX   64
#define D_ACC  32
#define H_DIM  64

// Scatter-add x_acc[src] into sum[dst], and count degrees.
// 8 threads per edge, each handling a float4 chunk of the 32-float account row.
__global__ __launch_bounds__(256) void scatter_kernel(
    const float* __restrict__ x_acc,
    const int*   __restrict__ src,
    const int*   __restrict__ dst,
    float*       __restrict__ sum,
    float*       __restrict__ cnt) {
    int t = blockIdx.x * blockDim.x + threadIdx.x;
    int e = t >> 3;
    if (e >= E_CNT) return;
    int q = t & 7;
    int s = src[e];
    int d = dst[e];
    float4 v = ((const float4*)(x_acc + (size_t)s * D_ACC))[q];
    float* p = sum + (size_t)d * D_ACC + q * 4;
    atomicAdd(p + 0, v.x);
    atomicAdd(p + 1, v.y);
    atomicAdd(p + 2, v.z);
    atomicAdd(p + 3, v.w);
    if (q == 0) atomicAdd(cnt + d, 1.0f);
}

// One wave per tx row; lane = output channel j.
// Lane j holds column j of Wl (32 floats) and Wr (64 floats) in VGPRs.
// Row data is read through wave-uniform addresses (readfirstlane) so the
// compiler can scalarize (s_load + v_fmac with SGPR operand).
// inv(count) is applied ONCE at the end (linearity), not per element.
__global__ __launch_bounds__(256, 2) void row_kernel(
    const float* __restrict__ x_tx,
    const float* __restrict__ sum,
    const float* __restrict__ cnt,
    const float* __restrict__ Wl,    // [D_ACC][H]
    const float* __restrict__ bl,    // [H]
    const float* __restrict__ Wr,    // [D_TX][H]
    const float* __restrict__ Wout,  // [H]
    const float* __restrict__ bout,  // [1]
    float*       __restrict__ logits,
    float*       __restrict__ txx,
    int total_waves) {
    int lane = threadIdx.x & 63;
    int wave = (blockIdx.x * blockDim.x + threadIdx.x) >> 6;

    // Preload this lane's weight columns (coalesced across lanes).
    float wl[D_ACC];
#pragma unroll
    for (int k = 0; k < D_ACC; ++k) wl[k] = Wl[k * H_DIM + lane];
    float wr[D_TX];
#pragma unroll
    for (int k = 0; k < D_TX; ++k) wr[k] = Wr[k * H_DIM + lane];
    float wo = Wout[lane];
    float b  = bl[lane];
    float bo = bout[0];

    for (int row = wave; row < N_TX; row += total_waves) {
        int urow = __builtin_amdgcn_readfirstlane(row);
        const float* srow = sum + (size_t)urow * D_ACC;
        const float* xrow = x_tx + (size_t)urow * D_TX;

        float c   = cnt[urow];
        float inv = 1.0f / fmaxf(c, 1.0f);

        float ha = 0.0f;
#pragma unroll
        for (int k = 0; k < D_ACC; ++k) ha = fmaf(srow[k], wl[k], ha);

        float hx = b;
#pragma unroll
        for (int k = 0; k < D_TX; ++k) hx = fmaf(xrow[k], wr[k], hx);

        float h = fmaf(ha, inv, hx);   // mean applied once
        float r = fmaxf(h, 0.0f);
        txx[(size_t)urow * H_DIM + lane] = r;

        // logits = relu(h) . Wout + bout  — wave reduction over 64 lanes
        float p = r * wo;
#pragma unroll
        for (int off = 32; off > 0; off >>= 1) p += __shfl_down(p, off);
        if (lane == 0) logits[urow] = p + bo;
    }
}

extern "C" void kernel_launch(void* const* d_in, const int* in_sizes, int n_in,
                              void* d_out, int out_size, void* d_ws, size_t ws_size,
                              hipStream_t stream) {
    const float* x_tx     = (const float*)d_in[0];
    const float* x_acc    = (const float*)d_in[1];
    const int*   pays_src = (const int*)d_in[2];
    const int*   pays_dst = (const int*)d_in[3];
    // d_in[4], d_in[5]: rev edges — unused (h_acc is dead in the reference)
    const float* Wl   = (const float*)d_in[6];
    const float* bl   = (const float*)d_in[7];
    const float* Wr   = (const float*)d_in[8];
    // d_in[9..11]: rev weights — unused
    const float* Wout = (const float*)d_in[12];
    const float* bout = (const float*)d_in[13];

    float* out    = (float*)d_out;
    float* logits = out;              // [N_TX]
    float* txx    = out + N_TX;       // [N_TX][H]

    float* sum = (float*)d_ws;                        // [N_TX][D_ACC]
    float* cnt = sum + (size_t)N_TX * D_ACC;          // [N_TX]

    size_t zero_bytes = ((size_t)N_TX * D_ACC + N_TX) * sizeof(float);
    hipMemsetAsync(d_ws, 0, zero_bytes, stream);

    int sc_threads = E_CNT * 8;
    scatter_kernel<<<(sc_threads + 255) / 256, 256, 0, stream>>>(
        x_acc, pays_src, pays_dst, sum, cnt);

    const int blocks = 2048;  // 4 waves/block -> 8192 waves, ~61 rows/wave
    row_kernel<<<blocks, 256, 0, stream>>>(
        x_tx, sum, cnt, Wl, bl, Wr, Wout, bout, logits, txx, blocks * 4);
}

// Round 2
// 724.324 us; speedup vs baseline: 1.3869x; 1.3869x over previous
//
#include <hip/hip_runtime.h>

#define N_TX   500000
#define N_ACC  100000
#define E_CNT  1000000
#define D_TX   64
#define D_ACC  32
#define H_DIM  64

#define SCAN_B    256
#define SCAN_I    8
#define SCAN_TILE (SCAN_B * SCAN_I)                         // 2048
#define NSCAN_BLOCKS ((N_TX + SCAN_TILE - 1) / SCAN_TILE)   // 245

// ---- CSR build ------------------------------------------------------------

__global__ __launch_bounds__(256) void hist_kernel(
    const int* __restrict__ dst, int* __restrict__ cnt) {
    int e = blockIdx.x * blockDim.x + threadIdx.x;
    if (e < E_CNT) atomicAdd(&cnt[dst[e]], 1);
}

// Block-level exclusive scan of cnt -> offs (block-local), block totals -> bsum
__global__ __launch_bounds__(SCAN_B) void scan1_kernel(
    const int* __restrict__ cnt, int* __restrict__ offs, int* __restrict__ bsum) {
    __shared__ int lds[SCAN_B];
    int base = blockIdx.x * SCAN_TILE + threadIdx.x * SCAN_I;
    int v[SCAN_I];
    int tsum = 0;
#pragma unroll
    for (int i = 0; i < SCAN_I; ++i) {
        int idx = base + i;
        v[i] = (idx < N_TX) ? cnt[idx] : 0;
        tsum += v[i];
    }
    lds[threadIdx.x] = tsum;
    __syncthreads();
    for (int off = 1; off < SCAN_B; off <<= 1) {
        int a = 0;
        if ((int)threadIdx.x >= off) a = lds[threadIdx.x - off];
        __syncthreads();
        lds[threadIdx.x] += a;
        __syncthreads();
    }
    int texcl = lds[threadIdx.x] - tsum;
    if (threadIdx.x == SCAN_B - 1) bsum[blockIdx.x] = lds[SCAN_B - 1];
    int run = texcl;
#pragma unroll
    for (int i = 0; i < SCAN_I; ++i) {
        int idx = base + i;
        if (idx < N_TX) offs[idx] = run;
        run += v[i];
    }
}

// Single-block exclusive scan of the 245 block sums
__global__ __launch_bounds__(256) void scan2_kernel(int* __restrict__ bsum, int nb) {
    __shared__ int lds[256];
    int t = threadIdx.x;
    int v = (t < nb) ? bsum[t] : 0;
    lds[t] = v;
    __syncthreads();
    for (int off = 1; off < 256; off <<= 1) {
        int a = 0;
        if (t >= off) a = lds[t - off];
        __syncthreads();
        lds[t] += a;
        __syncthreads();
    }
    if (t < nb) bsum[t] = lds[t] - v;  // exclusive
}

__global__ __launch_bounds__(256) void finalize_kernel(
    int* __restrict__ offs, int* __restrict__ cursors, const int* __restrict__ bsum) {
    int i = blockIdx.x * blockDim.x + threadIdx.x;
    if (i < N_TX) {
        int f = offs[i] + bsum[i / SCAN_TILE];
        offs[i] = f;
        cursors[i] = f;
    }
}

__global__ __launch_bounds__(256) void fill_kernel(
    const int* __restrict__ src, const int* __restrict__ dst,
    int* __restrict__ cursors, int* __restrict__ eidx) {
    int e = blockIdx.x * blockDim.x + threadIdx.x;
    if (e < E_CNT) {
        int d = dst[e];
        int p = atomicAdd(&cursors[d], 1);
        eidx[p] = src[e];
    }
}

// ---- Fused row kernel -----------------------------------------------------
// One wave per tx row; lane = output channel j. Weight columns in VGPRs
// (96 regs). Row data via float4 broadcast loads (same addr all lanes).
// CSR gather folded into the dot product: agg@Wl = (sum_e x_acc[s_e]@Wl)/deg.
__global__ __launch_bounds__(256, 4) void row_kernel(
    const float* __restrict__ x_tx,
    const float* __restrict__ x_acc,
    const int*   __restrict__ offs,
    const int*   __restrict__ cnt,
    const int*   __restrict__ eidx,
    const float* __restrict__ Wl,    // [D_ACC][H]
    const float* __restrict__ bl,    // [H]
    const float* __restrict__ Wr,    // [D_TX][H]
    const float* __restrict__ Wout,  // [H]
    const float* __restrict__ bout,  // [1]
    float*       __restrict__ logits,
    float*       __restrict__ txx,
    int total_waves) {
    int lane = threadIdx.x & 63;
    int wave = (blockIdx.x * blockDim.x + threadIdx.x) >> 6;

    float wl[D_ACC];
#pragma unroll
    for (int k = 0; k < D_ACC; ++k) wl[k] = Wl[k * H_DIM + lane];
    float wr[D_TX];
#pragma unroll
    for (int k = 0; k < D_TX; ++k) wr[k] = Wr[k * H_DIM + lane];
    float wo = Wout[lane];
    float b  = bl[lane];
    float bo = bout[0];

    for (int row = wave; row < N_TX; row += total_waves) {
        int urow = __builtin_amdgcn_readfirstlane(row);

        // dense part: x_tx[row] . wr  (4 independent chains of 16)
        const float4* xr = (const float4*)(x_tx + (size_t)urow * D_TX);
        float a0 = 0.f, a1 = 0.f, a2 = 0.f, a3 = 0.f;
#pragma unroll
        for (int q = 0; q < 16; ++q) {
            float4 v = xr[q];
            a0 = fmaf(v.x, wr[4 * q + 0], a0);
            a1 = fmaf(v.y, wr[4 * q + 1], a1);
            a2 = fmaf(v.z, wr[4 * q + 2], a2);
            a3 = fmaf(v.w, wr[4 * q + 3], a3);
        }
        float hx = (a0 + a1) + (a2 + a3) + b;

        // gathered part: sum over in-edges of x_acc[src] . wl
        int deg = __builtin_amdgcn_readfirstlane(cnt[urow]);
        int off = __builtin_amdgcn_readfirstlane(offs[urow]);
        float g0 = 0.f, g1 = 0.f, g2 = 0.f, g3 = 0.f;
        for (int e = 0; e < deg; ++e) {
            int s = __builtin_amdgcn_readfirstlane(eidx[off + e]);
            const float4* ar = (const float4*)(x_acc + (size_t)s * D_ACC);
#pragma unroll
            for (int q = 0; q < 8; ++q) {
                float4 v = ar[q];
                g0 = fmaf(v.x, wl[4 * q + 0], g0);
                g1 = fmaf(v.y, wl[4 * q + 1], g1);
                g2 = fmaf(v.z, wl[4 * q + 2], g2);
                g3 = fmaf(v.w, wl[4 * q + 3], g3);
            }
        }
        float ha  = (g0 + g1) + (g2 + g3);
        float inv = 1.0f / (float)(deg > 0 ? deg : 1);

        float h = fmaf(ha, inv, hx);
        float r = fmaxf(h, 0.0f);
        txx[(size_t)urow * H_DIM + lane] = r;

        float p = r * wo;
#pragma unroll
        for (int s = 32; s > 0; s >>= 1) p += __shfl_down(p, s);
        if (lane == 0) logits[urow] = p + bo;
    }
}

extern "C" void kernel_launch(void* const* d_in, const int* in_sizes, int n_in,
                              void* d_out, int out_size, void* d_ws, size_t ws_size,
                              hipStream_t stream) {
    const float* x_tx     = (const float*)d_in[0];
    const float* x_acc    = (const float*)d_in[1];
    const int*   pays_src = (const int*)d_in[2];
    const int*   pays_dst = (const int*)d_in[3];
    // d_in[4], d_in[5]: rev edges — unused (h_acc is dead in the reference)
    const float* Wl   = (const float*)d_in[6];
    const float* bl   = (const float*)d_in[7];
    const float* Wr   = (const float*)d_in[8];
    // d_in[9..11]: rev weights — unused
    const float* Wout = (const float*)d_in[12];
    const float* bout = (const float*)d_in[13];

    float* out    = (float*)d_out;
    float* logits = out;            // [N_TX]
    float* txx    = out + N_TX;     // [N_TX][H]

    // workspace layout (ints)
    int* cnt     = (int*)d_ws;           // [N_TX]
    int* offs    = cnt + N_TX;           // [N_TX]
    int* cursors = offs + N_TX;          // [N_TX]
    int* bsum    = cursors + N_TX;       // [1024 pad]
    int* eidx    = bsum + 1024;          // [E]

    hipMemsetAsync(cnt, 0, (size_t)N_TX * sizeof(int), stream);

    hist_kernel<<<(E_CNT + 255) / 256, 256, 0, stream>>>(pays_dst, cnt);
    scan1_kernel<<<NSCAN_BLOCKS, SCAN_B, 0, stream>>>(cnt, offs, bsum);
    scan2_kernel<<<1, 256, 0, stream>>>(bsum, NSCAN_BLOCKS);
    finalize_kernel<<<(N_TX + 255) / 256, 256, 0, stream>>>(offs, cursors, bsum);
    fill_kernel<<<(E_CNT + 255) / 256, 256, 0, stream>>>(pays_src, pays_dst, cursors, eidx);

    const int blocks = 2048;  // 4 waves/block -> 8192 waves
    row_kernel<<<blocks, 256, 0, stream>>>(
        x_tx, x_acc, offs, cnt, eidx, Wl, bl, Wr, Wout, bout,
        logits, txx, blocks * 4);
}

// Round 3
// 677.751 us; speedup vs baseline: 1.4822x; 1.0687x over previous
//
#include <hip/hip_runtime.h>

#define N_TX   500000
#define N_ACC  100000
#define E_CNT  1000000
#define D_TX   64
#define D_ACC  32
#define H_DIM  64

#define SCAN_B    256
#define SCAN_I    8
#define SCAN_TILE (SCAN_B * SCAN_I)                         // 2048
#define NSCAN_BLOCKS ((N_TX + SCAN_TILE - 1) / SCAN_TILE)   // 245

// ---- CSR build ------------------------------------------------------------

__global__ __launch_bounds__(256) void hist_kernel(
    const int* __restrict__ dst, int* __restrict__ cnt) {
    int e = blockIdx.x * blockDim.x + threadIdx.x;
    if (e < E_CNT) atomicAdd(&cnt[dst[e]], 1);
}

__global__ __launch_bounds__(SCAN_B) void scan1_kernel(
    const int* __restrict__ cnt, int* __restrict__ offs, int* __restrict__ bsum) {
    __shared__ int lds[SCAN_B];
    int base = blockIdx.x * SCAN_TILE + threadIdx.x * SCAN_I;
    int v[SCAN_I];
    int tsum = 0;
#pragma unroll
    for (int i = 0; i < SCAN_I; ++i) {
        int idx = base + i;
        v[i] = (idx < N_TX) ? cnt[idx] : 0;
        tsum += v[i];
    }
    lds[threadIdx.x] = tsum;
    __syncthreads();
    for (int off = 1; off < SCAN_B; off <<= 1) {
        int a = 0;
        if ((int)threadIdx.x >= off) a = lds[threadIdx.x - off];
        __syncthreads();
        lds[threadIdx.x] += a;
        __syncthreads();
    }
    int texcl = lds[threadIdx.x] - tsum;
    if (threadIdx.x == SCAN_B - 1) bsum[blockIdx.x] = lds[SCAN_B - 1];
    int run = texcl;
#pragma unroll
    for (int i = 0; i < SCAN_I; ++i) {
        int idx = base + i;
        if (idx < N_TX) offs[idx] = run;
        run += v[i];
    }
}

__global__ __launch_bounds__(256) void scan2_kernel(int* __restrict__ bsum, int nb) {
    __shared__ int lds[256];
    int t = threadIdx.x;
    int v = (t < nb) ? bsum[t] : 0;
    lds[t] = v;
    __syncthreads();
    for (int off = 1; off < 256; off <<= 1) {
        int a = 0;
        if (t >= off) a = lds[t - off];
        __syncthreads();
        lds[t] += a;
        __syncthreads();
    }
    if (t < nb) bsum[t] = lds[t] - v;  // exclusive
}

__global__ __launch_bounds__(256) void finalize_kernel(
    int* __restrict__ offs, int* __restrict__ cursors, const int* __restrict__ bsum) {
    int i = blockIdx.x * blockDim.x + threadIdx.x;
    if (i < N_TX) {
        int f = offs[i] + bsum[i / SCAN_TILE];
        offs[i] = f;
        cursors[i] = f;
    }
}

__global__ __launch_bounds__(256) void fill_kernel(
    const int* __restrict__ src, const int* __restrict__ dst,
    int* __restrict__ cursors, int* __restrict__ eidx) {
    int e = blockIdx.x * blockDim.x + threadIdx.x;
    if (e < E_CNT) {
        int d = dst[e];
        int p = atomicAdd(&cursors[d], 1);
        eidx[p] = src[e];
    }
}

// ---- y = x_acc @ Wl  (no bias; bl is added per-tx-row in row_kernel) ------
// Wave per contiguous row range; lane = channel. wl column resident in VGPRs.
__global__ __launch_bounds__(256, 4) void acc_transform_kernel(
    const float* __restrict__ x_acc, const float* __restrict__ Wl,
    float* __restrict__ y, int rows_per_wave) {
    int lane = threadIdx.x & 63;
    int wave = (blockIdx.x * blockDim.x + threadIdx.x) >> 6;
    float wl[D_ACC];
#pragma unroll
    for (int k = 0; k < D_ACC; ++k) wl[k] = Wl[k * H_DIM + lane];
    int r0 = wave * rows_per_wave;
    int r1 = min(r0 + rows_per_wave, N_ACC);
    for (int row = r0; row < r1; ++row) {
        int urow = __builtin_amdgcn_readfirstlane(row);
        const float4* xr = (const float4*)(x_acc + (size_t)urow * D_ACC);
        float a0 = 0.f, a1 = 0.f, a2 = 0.f, a3 = 0.f;
#pragma unroll
        for (int q = 0; q < 8; ++q) {
            float4 v = xr[q];
            a0 = fmaf(v.x, wl[4 * q + 0], a0);
            a1 = fmaf(v.y, wl[4 * q + 1], a1);
            a2 = fmaf(v.z, wl[4 * q + 2], a2);
            a3 = fmaf(v.w, wl[4 * q + 3], a3);
        }
        y[(size_t)urow * H_DIM + lane] = (a0 + a1) + (a2 + a3);
    }
}

// ---- Fused row kernel -----------------------------------------------------
// Wave per contiguous row range; lane = output channel.
// wr[64] column resident in VGPRs (only 64 now -> fits 128-reg budget).
// x_tx row via wave-uniform (scalar) loads; gather = coalesced y-row loads,
// software-pipelined 1 edge ahead.
__global__ __launch_bounds__(256, 4) void row_kernel(
    const float* __restrict__ x_tx,
    const float* __restrict__ y,
    const int*   __restrict__ offs,
    const int*   __restrict__ cnt,
    const int*   __restrict__ eidx,
    const float* __restrict__ Wr,    // [D_TX][H]
    const float* __restrict__ bl,    // [H]
    const float* __restrict__ Wout,  // [H]
    const float* __restrict__ bout,  // [1]
    float*       __restrict__ logits,
    float*       __restrict__ txx,
    int rows_per_wave) {
    int lane = threadIdx.x & 63;
    int wave = (blockIdx.x * blockDim.x + threadIdx.x) >> 6;

    float wr[D_TX];
#pragma unroll
    for (int k = 0; k < D_TX; ++k) wr[k] = Wr[k * H_DIM + lane];
    float b  = bl[lane];
    float wo = Wout[lane];
    float bo = bout[0];

    int r0 = wave * rows_per_wave;
    int r1 = min(r0 + rows_per_wave, N_TX);
    for (int row = r0; row < r1; ++row) {
        int urow = __builtin_amdgcn_readfirstlane(row);
        int deg = __builtin_amdgcn_readfirstlane(cnt[urow]);
        int off = __builtin_amdgcn_readfirstlane(offs[urow]);

        // issue first gather load early (overlaps with dense FMAs)
        float g = 0.f, v = 0.f;
        if (deg > 0) {
            int s0 = __builtin_amdgcn_readfirstlane(eidx[off]);
            v = y[(size_t)s0 * H_DIM + lane];
        }

        // dense: x_tx[row] . wr   (x elements wave-uniform -> scalar loads)
        const float4* xr = (const float4*)(x_tx + (size_t)urow * D_TX);
        float a0 = 0.f, a1 = 0.f, a2 = 0.f, a3 = 0.f;
#pragma unroll
        for (int q = 0; q < 16; ++q) {
            float4 xv = xr[q];
            a0 = fmaf(xv.x, wr[4 * q + 0], a0);
            a1 = fmaf(xv.y, wr[4 * q + 1], a1);
            a2 = fmaf(xv.z, wr[4 * q + 2], a2);
            a3 = fmaf(xv.w, wr[4 * q + 3], a3);
        }

        // remaining edges, 1-ahead pipelined
        for (int e = 1; e < deg; ++e) {
            int s2 = __builtin_amdgcn_readfirstlane(eidx[off + e]);
            float v2 = y[(size_t)s2 * H_DIM + lane];
            g += v;
            v = v2;
        }
        if (deg > 0) g += v;

        float inv = 1.0f / (float)(deg > 0 ? deg : 1);
        float h = ((a0 + a1) + (a2 + a3)) + b + g * inv;
        float r = fmaxf(h, 0.f);
        txx[(size_t)urow * H_DIM + lane] = r;

        float p = r * wo;
#pragma unroll
        for (int sh = 32; sh > 0; sh >>= 1) p += __shfl_down(p, sh);
        if (lane == 0) logits[urow] = p + bo;
    }
}

extern "C" void kernel_launch(void* const* d_in, const int* in_sizes, int n_in,
                              void* d_out, int out_size, void* d_ws, size_t ws_size,
                              hipStream_t stream) {
    const float* x_tx     = (const float*)d_in[0];
    const float* x_acc    = (const float*)d_in[1];
    const int*   pays_src = (const int*)d_in[2];
    const int*   pays_dst = (const int*)d_in[3];
    // d_in[4], d_in[5]: rev edges — unused (h_acc is dead in the reference)
    const float* Wl   = (const float*)d_in[6];
    const float* bl   = (const float*)d_in[7];
    const float* Wr   = (const float*)d_in[8];
    // d_in[9..11]: rev weights — unused
    const float* Wout = (const float*)d_in[12];
    const float* bout = (const float*)d_in[13];

    float* out    = (float*)d_out;
    float* logits = out;            // [N_TX]
    float* txx    = out + N_TX;     // [N_TX][H]

    // workspace layout
    int* cnt     = (int*)d_ws;           // [N_TX]
    int* offs    = cnt + N_TX;           // [N_TX]
    int* cursors = offs + N_TX;          // [N_TX]
    int* bsum    = cursors + N_TX;       // [1024 pad]
    int* eidx    = bsum + 1024;          // [E]
    float* y     = (float*)(eidx + E_CNT);  // [N_ACC][H] = 25.6 MB

    hipMemsetAsync(cnt, 0, (size_t)N_TX * sizeof(int), stream);

    hist_kernel<<<(E_CNT + 255) / 256, 256, 0, stream>>>(pays_dst, cnt);
    scan1_kernel<<<NSCAN_BLOCKS, SCAN_B, 0, stream>>>(cnt, offs, bsum);
    scan2_kernel<<<1, 256, 0, stream>>>(bsum, NSCAN_BLOCKS);
    finalize_kernel<<<(N_TX + 255) / 256, 256, 0, stream>>>(offs, cursors, bsum);
    fill_kernel<<<(E_CNT + 255) / 256, 256, 0, stream>>>(pays_src, pays_dst, cursors, eidx);

    // y = x_acc @ Wl : 512 blocks * 4 waves = 2048 waves
    {
        const int blocks = 512;
        int rpw = (N_ACC + blocks * 4 - 1) / (blocks * 4);  // 49
        acc_transform_kernel<<<blocks, 256, 0, stream>>>(x_acc, Wl, y, rpw);
    }

    // fused row kernel: 2048 blocks * 4 waves = 8192 waves
    {
        const int blocks = 2048;
        int rpw = (N_TX + blocks * 4 - 1) / (blocks * 4);   // 62
        row_kernel<<<blocks, 256, 0, stream>>>(
            x_tx, y, offs, cnt, eidx, Wr, bl, Wout, bout, logits, txx, rpw);
    }
}

// Round 4
// 669.190 us; speedup vs baseline: 1.5012x; 1.0128x over previous
//
#include <hip/hip_runtime.h>

#define N_TX   500000
#define N_ACC  100000
#define E_CNT  1000000
#define D_TX   64
#define D_ACC  32
#define H_DIM  64

#define SCAN_B    256
#define SCAN_I    8
#define SCAN_TILE (SCAN_B * SCAN_I)                         // 2048
#define NSCAN_BLOCKS ((N_TX + SCAN_TILE - 1) / SCAN_TILE)   // 245

// ---- CSR build ------------------------------------------------------------

__global__ __launch_bounds__(256) void hist_kernel(
    const int* __restrict__ dst, int* __restrict__ cnt) {
    int e = blockIdx.x * blockDim.x + threadIdx.x;
    if (e < E_CNT) atomicAdd(&cnt[dst[e]], 1);
}

__global__ __launch_bounds__(SCAN_B) void scan1_kernel(
    const int* __restrict__ cnt, int* __restrict__ offs, int* __restrict__ bsum) {
    __shared__ int lds[SCAN_B];
    int base = blockIdx.x * SCAN_TILE + threadIdx.x * SCAN_I;
    int v[SCAN_I];
    int tsum = 0;
#pragma unroll
    for (int i = 0; i < SCAN_I; ++i) {
        int idx = base + i;
        v[i] = (idx < N_TX) ? cnt[idx] : 0;
        tsum += v[i];
    }
    lds[threadIdx.x] = tsum;
    __syncthreads();
    for (int off = 1; off < SCAN_B; off <<= 1) {
        int a = 0;
        if ((int)threadIdx.x >= off) a = lds[threadIdx.x - off];
        __syncthreads();
        lds[threadIdx.x] += a;
        __syncthreads();
    }
    int texcl = lds[threadIdx.x] - tsum;
    if (threadIdx.x == SCAN_B - 1) bsum[blockIdx.x] = lds[SCAN_B - 1];
    int run = texcl;
#pragma unroll
    for (int i = 0; i < SCAN_I; ++i) {
        int idx = base + i;
        if (idx < N_TX) offs[idx] = run;
        run += v[i];
    }
}

__global__ __launch_bounds__(256) void scan2_kernel(int* __restrict__ bsum, int nb) {
    __shared__ int lds[256];
    int t = threadIdx.x;
    int v = (t < nb) ? bsum[t] : 0;
    lds[t] = v;
    __syncthreads();
    for (int off = 1; off < 256; off <<= 1) {
        int a = 0;
        if (t >= off) a = lds[t - off];
        __syncthreads();
        lds[t] += a;
        __syncthreads();
    }
    if (t < nb) bsum[t] = lds[t] - v;  // exclusive
}

__global__ __launch_bounds__(256) void finalize_kernel(
    int* __restrict__ offs, int* __restrict__ cursors, const int* __restrict__ bsum) {
    int i = blockIdx.x * blockDim.x + threadIdx.x;
    if (i < N_TX) {
        int f = offs[i] + bsum[i / SCAN_TILE];
        offs[i] = f;
        cursors[i] = f;
    }
}

__global__ __launch_bounds__(256) void fill_kernel(
    const int* __restrict__ src, const int* __restrict__ dst,
    int* __restrict__ cursors, int* __restrict__ eidx) {
    int e = blockIdx.x * blockDim.x + threadIdx.x;
    if (e < E_CNT) {
        int d = dst[e];
        int p = atomicAdd(&cursors[d], 1);
        eidx[p] = src[e];
    }
}

// ---- y = x_acc @ Wl -------------------------------------------------------
// Wave per contiguous row range; lane = channel. wl column PINNED in VGPRs
// via asm barrier (compiler otherwise sinks the invariant loads into the loop
// and re-fetches 8 KB/row through L1 -- observed as VGPR_Count=48 in r2/r3).
__global__ __launch_bounds__(256, 4) void acc_transform_kernel(
    const float* __restrict__ x_acc, const float* __restrict__ Wl,
    float* __restrict__ y, int rows_per_wave) {
    int lane = threadIdx.x & 63;
    int wave = (blockIdx.x * blockDim.x + threadIdx.x) >> 6;
    float wl[D_ACC];
#pragma unroll
    for (int k = 0; k < D_ACC; ++k) wl[k] = Wl[k * H_DIM + lane];
#pragma unroll
    for (int k = 0; k < D_ACC; ++k) asm volatile("" : "+v"(wl[k]));  // pin
    int r0 = wave * rows_per_wave;
    int r1 = min(r0 + rows_per_wave, N_ACC);
    for (int row = r0; row < r1; ++row) {
        int urow = __builtin_amdgcn_readfirstlane(row);
        const float4* xr = (const float4*)(x_acc + (size_t)urow * D_ACC);
        float a0 = 0.f, a1 = 0.f, a2 = 0.f, a3 = 0.f;
#pragma unroll
        for (int q = 0; q < 8; ++q) {
            float4 v = xr[q];
            a0 = fmaf(v.x, wl[4 * q + 0], a0);
            a1 = fmaf(v.y, wl[4 * q + 1], a1);
            a2 = fmaf(v.z, wl[4 * q + 2], a2);
            a3 = fmaf(v.w, wl[4 * q + 3], a3);
        }
        y[(size_t)urow * H_DIM + lane] = (a0 + a1) + (a2 + a3);
    }
}

// ---- Fused row kernel -----------------------------------------------------
// Wave per contiguous row range; lane = output channel.
// wr[64] column PINNED in VGPRs (asm barrier prevents load sinking).
// x_tx row via wave-uniform scalar loads; gather = coalesced y-row loads.
__global__ __launch_bounds__(256, 4) void row_kernel(
    const float* __restrict__ x_tx,
    const float* __restrict__ y,
    const int*   __restrict__ offs,
    const int*   __restrict__ cnt,
    const int*   __restrict__ eidx,
    const float* __restrict__ Wr,    // [D_TX][H]
    const float* __restrict__ bl,    // [H]
    const float* __restrict__ Wout,  // [H]
    const float* __restrict__ bout,  // [1]
    float*       __restrict__ logits,
    float*       __restrict__ txx,
    int rows_per_wave) {
    int lane = threadIdx.x & 63;
    int wave = (blockIdx.x * blockDim.x + threadIdx.x) >> 6;

    float wr[D_TX];
#pragma unroll
    for (int k = 0; k < D_TX; ++k) wr[k] = Wr[k * H_DIM + lane];
#pragma unroll
    for (int k = 0; k < D_TX; ++k) asm volatile("" : "+v"(wr[k]));  // pin
    float b  = bl[lane];
    float wo = Wout[lane];
    float bo = bout[0];
    asm volatile("" : "+v"(b), "+v"(wo), "+v"(bo));

    int r0 = wave * rows_per_wave;
    int r1 = min(r0 + rows_per_wave, N_TX);
    for (int row = r0; row < r1; ++row) {
        int urow = __builtin_amdgcn_readfirstlane(row);
        int deg = __builtin_amdgcn_readfirstlane(cnt[urow]);
        int off = __builtin_amdgcn_readfirstlane(offs[urow]);

        // issue first gather load early (overlaps the dense FMA block)
        float g = 0.f, v = 0.f;
        if (deg > 0) {
            int s0 = __builtin_amdgcn_readfirstlane(eidx[off]);
            v = y[(size_t)s0 * H_DIM + lane];
        }

        // dense: x_tx[row] . wr   (x elements wave-uniform -> scalar loads)
        const float4* xr = (const float4*)(x_tx + (size_t)urow * D_TX);
        float a0 = 0.f, a1 = 0.f, a2 = 0.f, a3 = 0.f;
#pragma unroll
        for (int q = 0; q < 16; ++q) {
            float4 xv = xr[q];
            a0 = fmaf(xv.x, wr[4 * q + 0], a0);
            a1 = fmaf(xv.y, wr[4 * q + 1], a1);
            a2 = fmaf(xv.z, wr[4 * q + 2], a2);
            a3 = fmaf(xv.w, wr[4 * q + 3], a3);
        }

        // remaining edges, 1-ahead pipelined
        for (int e = 1; e < deg; ++e) {
            int s2 = __builtin_amdgcn_readfirstlane(eidx[off + e]);
            float v2 = y[(size_t)s2 * H_DIM + lane];
            g += v;
            v = v2;
        }
        if (deg > 0) g += v;

        float inv = 1.0f / (float)(deg > 0 ? deg : 1);
        float h = ((a0 + a1) + (a2 + a3)) + b + g * inv;
        float r = fmaxf(h, 0.f);
        txx[(size_t)urow * H_DIM + lane] = r;

        float p = r * wo;
#pragma unroll
        for (int sh = 32; sh > 0; sh >>= 1) p += __shfl_down(p, sh);
        if (lane == 0) logits[urow] = p + bo;
    }
}

extern "C" void kernel_launch(void* const* d_in, const int* in_sizes, int n_in,
                              void* d_out, int out_size, void* d_ws, size_t ws_size,
                              hipStream_t stream) {
    const float* x_tx     = (const float*)d_in[0];
    const float* x_acc    = (const float*)d_in[1];
    const int*   pays_src = (const int*)d_in[2];
    const int*   pays_dst = (const int*)d_in[3];
    // d_in[4], d_in[5]: rev edges — unused (h_acc is dead in the reference)
    const float* Wl   = (const float*)d_in[6];
    const float* bl   = (const float*)d_in[7];
    const float* Wr   = (const float*)d_in[8];
    // d_in[9..11]: rev weights — unused
    const float* Wout = (const float*)d_in[12];
    const float* bout = (const float*)d_in[13];

    float* out    = (float*)d_out;
    float* logits = out;            // [N_TX]
    float* txx    = out + N_TX;     // [N_TX][H]

    // workspace layout
    int* cnt     = (int*)d_ws;           // [N_TX]
    int* offs    = cnt + N_TX;           // [N_TX]
    int* cursors = offs + N_TX;          // [N_TX]
    int* bsum    = cursors + N_TX;       // [1024 pad]
    int* eidx    = bsum + 1024;          // [E]
    float* y     = (float*)(eidx + E_CNT);  // [N_ACC][H] = 25.6 MB

    hipMemsetAsync(cnt, 0, (size_t)N_TX * sizeof(int), stream);

    hist_kernel<<<(E_CNT + 255) / 256, 256, 0, stream>>>(pays_dst, cnt);
    scan1_kernel<<<NSCAN_BLOCKS, SCAN_B, 0, stream>>>(cnt, offs, bsum);
    scan2_kernel<<<1, 256, 0, stream>>>(bsum, NSCAN_BLOCKS);
    finalize_kernel<<<(N_TX + 255) / 256, 256, 0, stream>>>(offs, cursors, bsum);
    fill_kernel<<<(E_CNT + 255) / 256, 256, 0, stream>>>(pays_src, pays_dst, cursors, eidx);

    // y = x_acc @ Wl : 1024 blocks * 4 waves = 4096 waves
    {
        const int blocks = 1024;
        int rpw = (N_ACC + blocks * 4 - 1) / (blocks * 4);  // 25
        acc_transform_kernel<<<blocks, 256, 0, stream>>>(x_acc, Wl, y, rpw);
    }

    // fused row kernel: 2048 blocks * 4 waves = 8192 waves
    {
        const int blocks = 2048;
        int rpw = (N_TX + blocks * 4 - 1) / (blocks * 4);   // 62
        row_kernel<<<blocks, 256, 0, stream>>>(
            x_tx, y, offs, cnt, eidx, Wr, bl, Wout, bout, logits, txx, rpw);
    }
}